// Round 1
// baseline (9675.437 us; speedup 1.0000x reference)
//
#include <hip/hip_runtime.h>
#include <cstdint>
#include <cstddef>

// ---------------- problem constants ----------------
#define T_STEPS 2048
#define NBATCH  64
#define HID     256
#define NGATE   1024            // 4*HID
#define NROWS   (T_STEPS*NBATCH) // 131072 rows of G

// recurrent kernel weight split: K=256 -> KR in VGPRs, rest in LDS
#define KR   192
#define KRC  24                 // KR/8 (uint4 chunks of 8 halves)
#define KLC  8                  // (256-KR)/8
#define REC_LDS_BYTES (KLC*1024*16 + 4096 + 512)  // lds_w + gates(f32x1024) + h(f16x256)

typedef _Float16 f16x8 __attribute__((ext_vector_type(8)));
typedef _Float16 h2f   __attribute__((ext_vector_type(2)));
typedef float    f32x4 __attribute__((ext_vector_type(4)));

__device__ __forceinline__ unsigned short f2h_bits(float f) {
    _Float16 h = (_Float16)f;
    return __builtin_bit_cast(unsigned short, h);
}
__device__ __forceinline__ float h2f_scalar(unsigned short u) {
    return (float)__builtin_bit_cast(_Float16, u);
}
__device__ __forceinline__ h2f bch(unsigned int u) {
    return __builtin_bit_cast(h2f, u);
}

// ---------------- workspace layout (bytes) ----------------
#define OFF_G    ((size_t)0)                    // 131072*1024 fp16 = 268435456 (aliased G0/G1)
#define OFF_Y0   ((size_t)268435456)            // 2048*64*256 fp16 = 67108864
#define OFF_WT0  ((size_t)335544320)            // 1024*256 fp16 (w_hh0 transposed)
#define OFF_WT1  ((size_t)336068608)
#define OFF_LW0  ((size_t)336592896)            // KLC*1024*8 fp16 = 131072 B
#define OFF_LW1  ((size_t)336723968)
#define OFF_BS0  ((size_t)336855040)            // 128*1024 fp16 swizzled = 262144 B
#define OFF_BS1  ((size_t)337117184)            // 256*1024 fp16 swizzled = 524288 B
#define WS_NEED  ((size_t)337641472)

// ---------------- weight conversion / swizzle ----------------
__global__ void convert_weights(const float* __restrict__ w_ih0, const float* __restrict__ w_hh0,
                                const float* __restrict__ w_ih1, const float* __restrict__ w_hh1,
                                unsigned short* __restrict__ WT0, unsigned short* __restrict__ WT1,
                                unsigned short* __restrict__ LW0, unsigned short* __restrict__ LW1,
                                unsigned short* __restrict__ BS0, unsigned short* __restrict__ BS1)
{
    int gid = blockIdx.x * blockDim.x + threadIdx.x;
    int gsz = gridDim.x * blockDim.x;
    // WT[j][k] = w_hh[k][j]  (1024 x 256)
    for (int s = gid; s < 1024 * 256; s += gsz) {
        int j = s >> 8, k = s & 255;
        WT0[s] = f2h_bits(w_hh0[k * 1024 + j]);
        WT1[s] = f2h_bits(w_hh1[k * 1024 + j]);
    }
    // LW[(c*1024+j)*8+i] = w_hh[KR + c*8 + i][j]
    for (int s = gid; s < KLC * 1024 * 8; s += gsz) {
        int i = s & 7, j = (s >> 3) & 1023, c = s >> 13;
        int k = KR + c * 8 + i;
        LW0[s] = f2h_bits(w_hh0[k * 1024 + j]);
        LW1[s] = f2h_bits(w_hh1[k * 1024 + j]);
    }
    // Bswz layer0: K=128 (KB=4): s = ((n16*KB+kb)*64+lane)*8+i
    for (int s = gid; s < 131072; s += gsz) {
        int i = s & 7, lane = (s >> 3) & 63, kb = (s >> 9) & 3, n16 = s >> 11;
        int k = kb * 32 + (lane >> 4) * 8 + i;
        int n = n16 * 16 + (lane & 15);
        BS0[s] = f2h_bits(w_ih0[k * 1024 + n]);
    }
    // Bswz layer1: K=256 (KB=8)
    for (int s = gid; s < 262144; s += gsz) {
        int i = s & 7, lane = (s >> 3) & 63, kb = (s >> 9) & 7, n16 = s >> 12;
        int k = kb * 32 + (lane >> 4) * 8 + i;
        int n = n16 * 16 + (lane & 15);
        BS1[s] = f2h_bits(w_ih1[k * 1024 + n]);
    }
}

// ---------------- input-gate GEMM: G[r][n] = A[map(r)][:] @ w_ih[:, n] + b[n] ----------------
// r = t*64 + b ; layer0: A = x fp32, row (b*2048 + 2047-t), K=128
//                layer1: A = y0 fp16, row ((2047-t)*64 + b), K=256
// per wave: 32 rows x 64 cols, MFMA 16x16x32 f16, no LDS
template <int KB, int LAYER>
__global__ __launch_bounds__(256) void gemm_in(const float* __restrict__ A32,
                                               const unsigned short* __restrict__ A16,
                                               const unsigned short* __restrict__ Bsw,
                                               const float* __restrict__ bias,
                                               unsigned short* __restrict__ Gout)
{
    const int lane = threadIdx.x & 63;
    const int wave = threadIdx.x >> 6;
    const int nblk = blockIdx.x & 15;        // 16 n-blocks of 64 cols
    const int rblk = blockIdx.x >> 4;        // 1024 r-blocks of 128 rows
    const int r0 = rblk * 128 + wave * 32;
    const int quad = lane >> 4, ln = lane & 15;

    f32x4 acc[2][4];
#pragma unroll
    for (int q = 0; q < 4; q++) {
        float bv = bias[(nblk * 4 + q) * 16 + ln];
#pragma unroll
        for (int mt = 0; mt < 2; mt++) {
            acc[mt][q][0] = bv; acc[mt][q][1] = bv; acc[mt][q][2] = bv; acc[mt][q][3] = bv;
        }
    }
    const int ar0 = r0 + ln, ar1 = r0 + 16 + ln;
    size_t aoff0, aoff1;
    if (LAYER == 0) {
        aoff0 = ((size_t)(ar0 & 63) * 2048 + (size_t)(2047 - (ar0 >> 6))) * 128;
        aoff1 = ((size_t)(ar1 & 63) * 2048 + (size_t)(2047 - (ar1 >> 6))) * 128;
    } else {
        aoff0 = ((size_t)(2047 - (ar0 >> 6)) * 64 + (size_t)(ar0 & 63)) * 256;
        aoff1 = ((size_t)(2047 - (ar1 >> 6)) * 64 + (size_t)(ar1 & 63)) * 256;
    }
#pragma unroll
    for (int kb = 0; kb < KB; kb++) {
        const int k0 = kb * 32 + quad * 8;
        f16x8 a0, a1;
        if (LAYER == 0) {
            const float* p0 = A32 + aoff0 + k0;
            const float* p1 = A32 + aoff1 + k0;
            float4 fa = *(const float4*)(p0);
            float4 fb = *(const float4*)(p0 + 4);
            float4 fc = *(const float4*)(p1);
            float4 fd = *(const float4*)(p1 + 4);
            a0[0] = (_Float16)fa.x; a0[1] = (_Float16)fa.y; a0[2] = (_Float16)fa.z; a0[3] = (_Float16)fa.w;
            a0[4] = (_Float16)fb.x; a0[5] = (_Float16)fb.y; a0[6] = (_Float16)fb.z; a0[7] = (_Float16)fb.w;
            a1[0] = (_Float16)fc.x; a1[1] = (_Float16)fc.y; a1[2] = (_Float16)fc.z; a1[3] = (_Float16)fc.w;
            a1[4] = (_Float16)fd.x; a1[5] = (_Float16)fd.y; a1[6] = (_Float16)fd.z; a1[7] = (_Float16)fd.w;
        } else {
            a0 = *(const f16x8*)(A16 + aoff0 + k0);
            a1 = *(const f16x8*)(A16 + aoff1 + k0);
        }
#pragma unroll
        for (int q = 0; q < 4; q++) {
            f16x8 bq = *(const f16x8*)(Bsw + (((size_t)(nblk * 4 + q) * KB + kb) * 64 + lane) * 8);
            acc[0][q] = __builtin_amdgcn_mfma_f32_16x16x32_f16(a0, bq, acc[0][q], 0, 0, 0);
            acc[1][q] = __builtin_amdgcn_mfma_f32_16x16x32_f16(a1, bq, acc[1][q], 0, 0, 0);
        }
    }
    // C/D layout: col = lane&15, row = (lane>>4)*4 + reg
#pragma unroll
    for (int mt = 0; mt < 2; mt++)
#pragma unroll
        for (int q = 0; q < 4; q++)
#pragma unroll
            for (int rg = 0; rg < 4; rg++) {
                int row = r0 + mt * 16 + quad * 4 + rg;
                int col = (nblk * 4 + q) * 16 + ln;
                Gout[(size_t)row * 1024 + col] = f2h_bits(acc[mt][q][rg]);
            }
}

// ---------------- persistent recurrent kernel: 1 WG per batch element ----------------
// 512 threads; thread owns gate columns j0=tid, j1=tid+512.
// weights: KR k-values in VGPRs (from WT), KLC*8 k-values in LDS (from LW).
template <int LAYER>
__global__ __launch_bounds__(512, 2) void lstm_rec(const unsigned short* __restrict__ G,
                                                   const unsigned short* __restrict__ WT,
                                                   const unsigned short* __restrict__ LW,
                                                   unsigned short* __restrict__ Y0,
                                                   float* __restrict__ Out)
{
    extern __shared__ char smem[];
    unsigned short* lds_w = (unsigned short*)smem;                       // KLC*1024*8 halves
    float* lds_g = (float*)(smem + (size_t)KLC * 1024 * 16);             // 1024 f32 gates
    unsigned short* lds_h = (unsigned short*)(smem + (size_t)KLC * 1024 * 16 + 4096); // 256 f16

    const int b = blockIdx.x;
    const int tid = threadIdx.x;
    const int j0 = tid, j1 = tid + 512;

    // load register-resident weight columns (contiguous rows of WT = transposed w_hh)
    uint4 wr0[KRC], wr1[KRC];
    {
        const uint4* p0 = (const uint4*)(WT + (size_t)j0 * 256);
        const uint4* p1 = (const uint4*)(WT + (size_t)j1 * 256);
#pragma unroll
        for (int i = 0; i < KRC; i++) { wr0[i] = p0[i]; wr1[i] = p1[i]; }
    }
    // stage LDS-resident weights (pre-swizzled: chunk-major, contiguous per (c, j))
    {
        const uint4* src = (const uint4*)LW;
        uint4* dst = (uint4*)lds_w;
        for (int i = tid; i < KLC * 1024; i += 512) dst[i] = src[i];
    }
    if (tid < 256) lds_h[tid] = 0;
    float c = 0.f;
    // prefetch G row for t=0
    unsigned short gp0 = G[(size_t)b * 1024 + j0];
    unsigned short gp1 = G[(size_t)b * 1024 + j1];
    __syncthreads();

    for (int t = 0; t < T_STEPS; ++t) {
        float ga = h2f_scalar(gp0);
        float gb = h2f_scalar(gp1);
        {   // prefetch next step's input gates (independent of h)
            int tn = (t < T_STEPS - 1) ? t + 1 : t;
            const unsigned short* Gn = G + ((size_t)tn * 64 + b) * 1024;
            gp0 = Gn[j0]; gp1 = Gn[j1];
        }
        h2f a00 = {}, a01 = {}, a02 = {}, a03 = {};
        h2f a10 = {}, a11 = {}, a12 = {}, a13 = {};
        const uint4* hv = (const uint4*)lds_h;
#pragma unroll
        for (int ci = 0; ci < KRC; ++ci) {
            uint4 h4 = hv[ci];                       // wave-uniform broadcast read
            h2f h0 = bch(h4.x), h1 = bch(h4.y), h2v = bch(h4.z), h3 = bch(h4.w);
            uint4 w = wr0[ci];
            a00 += h0 * bch(w.x); a01 += h1 * bch(w.y); a02 += h2v * bch(w.z); a03 += h3 * bch(w.w);
            w = wr1[ci];
            a10 += h0 * bch(w.x); a11 += h1 * bch(w.y); a12 += h2v * bch(w.z); a13 += h3 * bch(w.w);
        }
        const uint4* wl = (const uint4*)lds_w;
#pragma unroll
        for (int ci = 0; ci < KLC; ++ci) {
            uint4 h4 = hv[KRC + ci];
            h2f h0 = bch(h4.x), h1 = bch(h4.y), h2v = bch(h4.z), h3 = bch(h4.w);
            uint4 w = wl[ci * 1024 + j0];
            a00 += h0 * bch(w.x); a01 += h1 * bch(w.y); a02 += h2v * bch(w.z); a03 += h3 * bch(w.w);
            w = wl[ci * 1024 + j1];
            a10 += h0 * bch(w.x); a11 += h1 * bch(w.y); a12 += h2v * bch(w.z); a13 += h3 * bch(w.w);
        }
        float gate0 = ga + ((float)a00.x + (float)a00.y) + ((float)a01.x + (float)a01.y)
                         + ((float)a02.x + (float)a02.y) + ((float)a03.x + (float)a03.y);
        float gate1 = gb + ((float)a10.x + (float)a10.y) + ((float)a11.x + (float)a11.y)
                         + ((float)a12.x + (float)a12.y) + ((float)a13.x + (float)a13.y);
        lds_g[j0] = gate0;
        lds_g[j1] = gate1;
        __syncthreads();
        if (tid < 256) {
            float f  = lds_g[tid];
            float ii = lds_g[tid + 256];
            float o  = lds_g[tid + 512];
            float g  = lds_g[tid + 768];
            float sf = 1.f / (1.f + __expf(-f));
            float si = 1.f / (1.f + __expf(-ii));
            float so = 1.f / (1.f + __expf(-o));
            float tg = 1.f - 2.f / (1.f + __expf(2.f * g));
            c = sf * c + si * tg;
            float tc = 1.f - 2.f / (1.f + __expf(2.f * c));
            float h = so * tc;
            lds_h[tid] = f2h_bits(h);
            if (LAYER == 0) {
                Y0[((size_t)t * 64 + b) * 256 + tid] = f2h_bits(h);
            } else {
                Out[((size_t)t * 64 + b) * 256 + tid] = h;   // y1 [T,B,H]
            }
            if (t == T_STEPS - 1) {
                Out[(size_t)33554432 + (size_t)LAYER * 16384 + (size_t)b * 256 + tid] = h;  // hn
                Out[(size_t)33554432 + 32768 + (size_t)LAYER * 16384 + (size_t)b * 256 + tid] = c; // cn
            }
        }
        __syncthreads();
    }
}

// ---------------- launch ----------------
extern "C" void kernel_launch(void* const* d_in, const int* in_sizes, int n_in,
                              void* d_out, int out_size, void* d_ws, size_t ws_size,
                              hipStream_t stream)
{
    const float* x     = (const float*)d_in[0];
    const float* w_ih0 = (const float*)d_in[1];
    const float* w_hh0 = (const float*)d_in[2];
    const float* b0    = (const float*)d_in[3];
    const float* w_ih1 = (const float*)d_in[4];
    const float* w_hh1 = (const float*)d_in[5];
    const float* b1    = (const float*)d_in[6];
    float* out = (float*)d_out;

    if (ws_size < WS_NEED) return;  // cannot run correctly; fail loudly (output stays poisoned)

    char* ws = (char*)d_ws;
    unsigned short* G   = (unsigned short*)(ws + OFF_G);
    unsigned short* Y0  = (unsigned short*)(ws + OFF_Y0);
    unsigned short* WT0 = (unsigned short*)(ws + OFF_WT0);
    unsigned short* WT1 = (unsigned short*)(ws + OFF_WT1);
    unsigned short* LW0 = (unsigned short*)(ws + OFF_LW0);
    unsigned short* LW1 = (unsigned short*)(ws + OFF_LW1);
    unsigned short* BS0 = (unsigned short*)(ws + OFF_BS0);
    unsigned short* BS1 = (unsigned short*)(ws + OFF_BS1);

    (void)hipFuncSetAttribute(reinterpret_cast<const void*>(&lstm_rec<0>),
                              hipFuncAttributeMaxDynamicSharedMemorySize, REC_LDS_BYTES);
    (void)hipFuncSetAttribute(reinterpret_cast<const void*>(&lstm_rec<1>),
                              hipFuncAttributeMaxDynamicSharedMemorySize, REC_LDS_BYTES);

    convert_weights<<<1024, 256, 0, stream>>>(w_ih0, w_hh0, w_ih1, w_hh1,
                                              WT0, WT1, LW0, LW1, BS0, BS1);
    gemm_in<4, 0><<<16384, 256, 0, stream>>>(x, nullptr, BS0, b0, G);
    lstm_rec<0><<<64, 512, REC_LDS_BYTES, stream>>>(G, WT0, LW0, Y0, out);
    gemm_in<8, 1><<<16384, 256, 0, stream>>>(nullptr, Y0, BS1, b1, G);
    lstm_rec<1><<<64, 512, REC_LDS_BYTES, stream>>>(G, WT1, LW1, Y0, out);
}

// Round 2
// 8210.278 us; speedup vs baseline: 1.1785x; 1.1785x over previous
//
#include <hip/hip_runtime.h>
#include <cstdint>
#include <cstddef>

// ---------------- problem constants ----------------
#define T_STEPS 2048
#define NBATCH  64
#define HID     256
#define NGATE   1024            // 4*HID

// recurrent kernel weight split: K=256 -> KR in VGPRs, rest in LDS
#define KR   192
#define KRC  24                 // KR/8 (uint4 chunks of 8 halves)
#define KLC  8                  // (256-KR)/8
#define REC_LDS_BYTES (KLC*1024*16 + 1024)  // lds_w (128 KB) + 2 x 256 f16 h buffers

typedef _Float16 f16x8 __attribute__((ext_vector_type(8)));
typedef _Float16 h2f   __attribute__((ext_vector_type(2)));
typedef float    f32x4 __attribute__((ext_vector_type(4)));

__device__ __forceinline__ unsigned short f2h_bits(float f) {
    _Float16 h = (_Float16)f;
    return __builtin_bit_cast(unsigned short, h);
}
__device__ __forceinline__ float h2f_scalar(unsigned short u) {
    return (float)__builtin_bit_cast(_Float16, u);
}

// fdot2: acc += a.x*b.x + a.y*b.y  (f32 accumulate, v_dot2_f32_f16, full rate)
__device__ __forceinline__ float fdot2u(unsigned int hh, unsigned int ww, float acc) {
#if __has_builtin(__builtin_amdgcn_fdot2)
    return __builtin_amdgcn_fdot2(__builtin_bit_cast(h2f, hh),
                                  __builtin_bit_cast(h2f, ww), acc, false);
#else
    h2f a = __builtin_bit_cast(h2f, hh), b = __builtin_bit_cast(h2f, ww);
    return acc + (float)a.x * (float)b.x + (float)a.y * (float)b.y;
#endif
}

// ---------------- workspace layout (bytes) ----------------
#define OFF_G    ((size_t)0)                    // 131072*1024 fp16 = 268435456 (aliased G0/G1)
#define OFF_Y0   ((size_t)268435456)            // 2048*64*256 fp16 = 67108864
#define OFF_WT0  ((size_t)335544320)            // 1024*256 fp16 (w_hh0 transposed)
#define OFF_WT1  ((size_t)336068608)
#define OFF_LW0  ((size_t)336592896)            // KLC*1024*8 fp16 = 131072 B
#define OFF_LW1  ((size_t)336723968)
#define OFF_BS0  ((size_t)336855040)            // 128*1024 fp16 swizzled = 262144 B
#define OFF_BS1  ((size_t)337117184)            // 256*1024 fp16 swizzled = 524288 B
#define WS_NEED  ((size_t)337641472)

// ---------------- weight conversion / swizzle ----------------
__global__ void convert_weights(const float* __restrict__ w_ih0, const float* __restrict__ w_hh0,
                                const float* __restrict__ w_ih1, const float* __restrict__ w_hh1,
                                unsigned short* __restrict__ WT0, unsigned short* __restrict__ WT1,
                                unsigned short* __restrict__ LW0, unsigned short* __restrict__ LW1,
                                unsigned short* __restrict__ BS0, unsigned short* __restrict__ BS1)
{
    int gid = blockIdx.x * blockDim.x + threadIdx.x;
    int gsz = gridDim.x * blockDim.x;
    // WT[j][k] = w_hh[k][j]  (1024 x 256)
    for (int s = gid; s < 1024 * 256; s += gsz) {
        int j = s >> 8, k = s & 255;
        WT0[s] = f2h_bits(w_hh0[k * 1024 + j]);
        WT1[s] = f2h_bits(w_hh1[k * 1024 + j]);
    }
    // LW[(c*1024+j)*8+i] = w_hh[KR + c*8 + i][j]
    for (int s = gid; s < KLC * 1024 * 8; s += gsz) {
        int i = s & 7, j = (s >> 3) & 1023, c = s >> 13;
        int k = KR + c * 8 + i;
        LW0[s] = f2h_bits(w_hh0[k * 1024 + j]);
        LW1[s] = f2h_bits(w_hh1[k * 1024 + j]);
    }
    // Bswz layer0: K=128 (KB=4): s = ((n16*KB+kb)*64+lane)*8+i
    for (int s = gid; s < 131072; s += gsz) {
        int i = s & 7, lane = (s >> 3) & 63, kb = (s >> 9) & 3, n16 = s >> 11;
        int k = kb * 32 + (lane >> 4) * 8 + i;
        int n = n16 * 16 + (lane & 15);
        BS0[s] = f2h_bits(w_ih0[k * 1024 + n]);
    }
    // Bswz layer1: K=256 (KB=8)
    for (int s = gid; s < 262144; s += gsz) {
        int i = s & 7, lane = (s >> 3) & 63, kb = (s >> 9) & 7, n16 = s >> 12;
        int k = kb * 32 + (lane >> 4) * 8 + i;
        int n = n16 * 16 + (lane & 15);
        BS1[s] = f2h_bits(w_ih1[k * 1024 + n]);
    }
}

// ---------------- input-gate GEMM: G[r][swz(n)] = A[map(r)][:] @ w_ih[:, n] + b[n] ----------------
// r = t*64 + b ; layer0: A = x fp32, row (b*2048 + 2047-t), K=128
//                layer1: A = y0 fp16, row ((2047-t)*64 + b), K=256
// G is stored gate-interleaved: col (gate*256+m) -> m*4+gate so the recurrent
// kernel reads both of a thread's gate values with ONE u32 load.
template <int KB, int LAYER>
__global__ __launch_bounds__(256) void gemm_in(const float* __restrict__ A32,
                                               const unsigned short* __restrict__ A16,
                                               const unsigned short* __restrict__ Bsw,
                                               const float* __restrict__ bias,
                                               unsigned short* __restrict__ Gout)
{
    const int lane = threadIdx.x & 63;
    const int wave = threadIdx.x >> 6;
    const int nblk = blockIdx.x & 15;        // 16 n-blocks of 64 cols
    const int rblk = blockIdx.x >> 4;        // 1024 r-blocks of 128 rows
    const int r0 = rblk * 128 + wave * 32;
    const int quad = lane >> 4, ln = lane & 15;

    f32x4 acc[2][4];
#pragma unroll
    for (int q = 0; q < 4; q++) {
        float bv = bias[(nblk * 4 + q) * 16 + ln];
#pragma unroll
        for (int mt = 0; mt < 2; mt++) {
            acc[mt][q][0] = bv; acc[mt][q][1] = bv; acc[mt][q][2] = bv; acc[mt][q][3] = bv;
        }
    }
    const int ar0 = r0 + ln, ar1 = r0 + 16 + ln;
    size_t aoff0, aoff1;
    if (LAYER == 0) {
        aoff0 = ((size_t)(ar0 & 63) * 2048 + (size_t)(2047 - (ar0 >> 6))) * 128;
        aoff1 = ((size_t)(ar1 & 63) * 2048 + (size_t)(2047 - (ar1 >> 6))) * 128;
    } else {
        aoff0 = ((size_t)(2047 - (ar0 >> 6)) * 64 + (size_t)(ar0 & 63)) * 256;
        aoff1 = ((size_t)(2047 - (ar1 >> 6)) * 64 + (size_t)(ar1 & 63)) * 256;
    }
#pragma unroll
    for (int kb = 0; kb < KB; kb++) {
        const int k0 = kb * 32 + quad * 8;
        f16x8 a0, a1;
        if (LAYER == 0) {
            const float* p0 = A32 + aoff0 + k0;
            const float* p1 = A32 + aoff1 + k0;
            float4 fa = *(const float4*)(p0);
            float4 fb = *(const float4*)(p0 + 4);
            float4 fc = *(const float4*)(p1);
            float4 fd = *(const float4*)(p1 + 4);
            a0[0] = (_Float16)fa.x; a0[1] = (_Float16)fa.y; a0[2] = (_Float16)fa.z; a0[3] = (_Float16)fa.w;
            a0[4] = (_Float16)fb.x; a0[5] = (_Float16)fb.y; a0[6] = (_Float16)fb.z; a0[7] = (_Float16)fb.w;
            a1[0] = (_Float16)fc.x; a1[1] = (_Float16)fc.y; a1[2] = (_Float16)fc.z; a1[3] = (_Float16)fc.w;
            a1[4] = (_Float16)fd.x; a1[5] = (_Float16)fd.y; a1[6] = (_Float16)fd.z; a1[7] = (_Float16)fd.w;
        } else {
            a0 = *(const f16x8*)(A16 + aoff0 + k0);
            a1 = *(const f16x8*)(A16 + aoff1 + k0);
        }
#pragma unroll
        for (int q = 0; q < 4; q++) {
            f16x8 bq = *(const f16x8*)(Bsw + (((size_t)(nblk * 4 + q) * KB + kb) * 64 + lane) * 8);
            acc[0][q] = __builtin_amdgcn_mfma_f32_16x16x32_f16(a0, bq, acc[0][q], 0, 0, 0);
            acc[1][q] = __builtin_amdgcn_mfma_f32_16x16x32_f16(a1, bq, acc[1][q], 0, 0, 0);
        }
    }
    // C/D layout: col = lane&15, row = (lane>>4)*4 + reg.  Store gate-interleaved.
#pragma unroll
    for (int mt = 0; mt < 2; mt++)
#pragma unroll
        for (int q = 0; q < 4; q++)
#pragma unroll
            for (int rg = 0; rg < 4; rg++) {
                int row = r0 + mt * 16 + quad * 4 + rg;
                int col = (nblk * 4 + q) * 16 + ln;
                int swz = ((col & 255) << 2) | (col >> 8);
                Gout[(size_t)row * 1024 + swz] = f2h_bits(acc[mt][q][rg]);
            }
}

// ---------------- persistent recurrent kernel: 1 WG per batch element ----------------
// 512 threads, 8 waves. Wave w, lane l: hidden unit m = w*32 + (l&31).
// Lanes l<32 own gate columns (f[m], i[m]); lanes l>=32 own (o[m], g[m]).
// After the dot products the 4 gates of unit m live in lanes l and l^32 of one
// wave -> exchange via __shfl_xor, epilogue computed redundantly by both lanes.
// ONE barrier per step; h double-buffered in LDS; G load issued and consumed
// within the same barrier interval; h-store deferred one step so no global op
// is outstanding at the barrier.
template <int LAYER>
__global__ __launch_bounds__(512, 2) void lstm_rec(const unsigned short* __restrict__ G,
                                                   const unsigned short* __restrict__ WT,
                                                   const unsigned short* __restrict__ LW,
                                                   unsigned short* __restrict__ Y0,
                                                   float* __restrict__ Out)
{
    extern __shared__ char smem[];
    unsigned short* lds_w  = (unsigned short*)smem;                         // KLC*1024 uint4
    unsigned short* lds_h0 = (unsigned short*)(smem + (size_t)KLC * 1024 * 16);  // 256 f16
    unsigned short* lds_h1 = lds_h0 + 256;                                  // 256 f16

    const int b = blockIdx.x;
    const int tid = threadIdx.x;
    const int wv = tid >> 6, l = tid & 63;
    const int upper = l >> 5;                 // 0 -> (f,i), 1 -> (o,g)
    const int m = wv * 32 + (l & 31);
    const int j0 = m + upper * 512;
    const int j1 = j0 + 256;

    // register-resident weight columns (rows of WT = transposed w_hh)
    uint4 wr0[KRC], wr1[KRC];
    {
        const uint4* p0 = (const uint4*)(WT + (size_t)j0 * 256);
        const uint4* p1 = (const uint4*)(WT + (size_t)j1 * 256);
#pragma unroll
        for (int i = 0; i < KRC; i++) { wr0[i] = p0[i]; wr1[i] = p1[i]; }
    }
    // stage LDS-resident weights
    {
        const uint4* src = (const uint4*)LW;
        uint4* dst = (uint4*)lds_w;
        for (int i = tid; i < KLC * 1024; i += 512) dst[i] = src[i];
    }
    if (tid < 256) lds_h0[tid] = 0;
    float c = 0.f, hprev = 0.f;
    __syncthreads();

    const unsigned int* Gb = (const unsigned int*)G + (size_t)b * 512;  // row stride 32768 uints

    for (int t = 0; t < T_STEPS; ++t) {
        // current step's input-gate pair: ONE u32 (consumed after dot loop, same interval)
        unsigned int gpack = Gb[(size_t)t * 32768 + m * 2 + upper];
        // deferred store of h_{t-1}: retires during the dot loop
        if (t && l < 32) {
            if (LAYER == 0) Y0[((size_t)(t - 1) * 64 + b) * 256 + m] = f2h_bits(hprev);
            else            Out[((size_t)(t - 1) * 64 + b) * 256 + m] = hprev;
        }
        const uint4* hv = (const uint4*)((t & 1) ? lds_h1 : lds_h0);
        float a00 = 0, a01 = 0, a02 = 0, a03 = 0;
        float a10 = 0, a11 = 0, a12 = 0, a13 = 0;
#pragma unroll
        for (int ci = 0; ci < KRC; ++ci) {
            uint4 h4 = hv[ci];                           // wave-uniform broadcast
            uint4 w = wr0[ci];
            a00 = fdot2u(h4.x, w.x, a00); a01 = fdot2u(h4.y, w.y, a01);
            a02 = fdot2u(h4.z, w.z, a02); a03 = fdot2u(h4.w, w.w, a03);
            w = wr1[ci];
            a10 = fdot2u(h4.x, w.x, a10); a11 = fdot2u(h4.y, w.y, a11);
            a12 = fdot2u(h4.z, w.z, a12); a13 = fdot2u(h4.w, w.w, a13);
        }
        {
            const uint4* wl = (const uint4*)lds_w;
#pragma unroll
            for (int ci = 0; ci < KLC; ++ci) {
                uint4 h4 = hv[KRC + ci];
                uint4 w = wl[ci * 1024 + j0];
                a00 = fdot2u(h4.x, w.x, a00); a01 = fdot2u(h4.y, w.y, a01);
                a02 = fdot2u(h4.z, w.z, a02); a03 = fdot2u(h4.w, w.w, a03);
                w = wl[ci * 1024 + j1];
                a10 = fdot2u(h4.x, w.x, a10); a11 = fdot2u(h4.y, w.y, a11);
                a12 = fdot2u(h4.z, w.z, a12); a13 = fdot2u(h4.w, w.w, a13);
            }
        }
        float v0 = h2f_scalar((unsigned short)(gpack & 0xffff)) + ((a00 + a01) + (a02 + a03));
        float v1 = h2f_scalar((unsigned short)(gpack >> 16))    + ((a10 + a11) + (a12 + a13));
        // exchange with partner lane (l ^ 32): gets the other gate pair
        float q0 = __shfl_xor(v0, 32, 64);
        float q1 = __shfl_xor(v1, 32, 64);
        float fg = upper ? q0 : v0;
        float ig = upper ? q1 : v1;
        float og = upper ? v0 : q0;
        float gg = upper ? v1 : q1;
        float sf = 1.f / (1.f + __expf(-fg));
        float si = 1.f / (1.f + __expf(-ig));
        float so = 1.f / (1.f + __expf(-og));
        float tg = 1.f - 2.f / (1.f + __expf(2.f * gg));
        c = sf * c + si * tg;
        float tc = 1.f - 2.f / (1.f + __expf(2.f * c));
        float h = so * tc;
        hprev = h;
        unsigned short* hn = (t & 1) ? lds_h0 : lds_h1;
        if (l < 32) hn[m] = f2h_bits(h);
        __syncthreads();
    }
    if (l < 32) {
        if (LAYER == 0) Y0[((size_t)(T_STEPS - 1) * 64 + b) * 256 + m] = f2h_bits(hprev);
        else            Out[((size_t)(T_STEPS - 1) * 64 + b) * 256 + m] = hprev;
        Out[(size_t)33554432 + (size_t)LAYER * 16384 + (size_t)b * 256 + m] = hprev;         // hn
        Out[(size_t)33554432 + 32768 + (size_t)LAYER * 16384 + (size_t)b * 256 + m] = c;     // cn
    }
}

// ---------------- launch ----------------
extern "C" void kernel_launch(void* const* d_in, const int* in_sizes, int n_in,
                              void* d_out, int out_size, void* d_ws, size_t ws_size,
                              hipStream_t stream)
{
    const float* x     = (const float*)d_in[0];
    const float* w_ih0 = (const float*)d_in[1];
    const float* w_hh0 = (const float*)d_in[2];
    const float* b0    = (const float*)d_in[3];
    const float* w_ih1 = (const float*)d_in[4];
    const float* w_hh1 = (const float*)d_in[5];
    const float* b1    = (const float*)d_in[6];
    float* out = (float*)d_out;

    if (ws_size < WS_NEED) return;  // cannot run correctly; fail loudly (output stays poisoned)

    char* ws = (char*)d_ws;
    unsigned short* G   = (unsigned short*)(ws + OFF_G);
    unsigned short* Y0  = (unsigned short*)(ws + OFF_Y0);
    unsigned short* WT0 = (unsigned short*)(ws + OFF_WT0);
    unsigned short* WT1 = (unsigned short*)(ws + OFF_WT1);
    unsigned short* LW0 = (unsigned short*)(ws + OFF_LW0);
    unsigned short* LW1 = (unsigned short*)(ws + OFF_LW1);
    unsigned short* BS0 = (unsigned short*)(ws + OFF_BS0);
    unsigned short* BS1 = (unsigned short*)(ws + OFF_BS1);

    (void)hipFuncSetAttribute(reinterpret_cast<const void*>(&lstm_rec<0>),
                              hipFuncAttributeMaxDynamicSharedMemorySize, REC_LDS_BYTES);
    (void)hipFuncSetAttribute(reinterpret_cast<const void*>(&lstm_rec<1>),
                              hipFuncAttributeMaxDynamicSharedMemorySize, REC_LDS_BYTES);

    convert_weights<<<1024, 256, 0, stream>>>(w_ih0, w_hh0, w_ih1, w_hh1,
                                              WT0, WT1, LW0, LW1, BS0, BS1);
    gemm_in<4, 0><<<16384, 256, 0, stream>>>(x, nullptr, BS0, b0, G);
    lstm_rec<0><<<64, 512, REC_LDS_BYTES, stream>>>(G, WT0, LW0, Y0, out);
    gemm_in<8, 1><<<16384, 256, 0, stream>>>(nullptr, Y0, BS1, b1, G);
    lstm_rec<1><<<64, 512, REC_LDS_BYTES, stream>>>(G, WT1, LW1, Y0, out);
}